// Round 9
// baseline (20531.631 us; speedup 1.0000x reference)
//
#include <hip/hip_runtime.h>
#include <hip/hip_bf16.h>
#include <math.h>

// Problem constants
#define B_    512
#define T_    256
#define DIN   64
#define DS    64
#define KK    128   // DIN + DS
#define NN    2048
#define DOUT  10

// Tiling: 512 WGs = NTILES(4) x BTILES(128), 256 thr, 2 WG/CU.
#define NT      512
#define BT      4
#define NTILES  (NN / NT)      // 4
#define BTILES  (B_ / BT)      // 128
#define THREADS 256
#define NWG     (NTILES * BTILES)   // 512

// Workspace (float offsets): ps double-buffer | Etb (bf16) | counters
#define PS1        ((size_t)BTILES * NTILES * BT * DS)   // 131072 floats (512 KB)
#define PS_TOT     (2 * PS1)
#define ETB_OFF    PS_TOT
#define ETB_FLOATS ((size_t)KK * NN / 2)                 // bf16 Et = 512 KB
#define BAR_OFF    (ETB_OFF + ETB_FLOATS)
#define BAR_UINTS  4096

__global__ __launch_bounds__(256) void pre_kernel(const float* __restrict__ enc,
                                                  float* __restrict__ ws,
                                                  float* __restrict__ out) {
    size_t i = (size_t)blockIdx.x * blockDim.x + threadIdx.x;
    size_t stride = (size_t)gridDim.x * blockDim.x;
    unsigned int* bar = (unsigned int*)(ws + BAR_OFF);
    for (size_t x = i; x < BAR_UINTS; x += stride) bar[x] = 0u;
    // Etb[k][n] = bf16_rn(enc[n][k])
    unsigned short* Etb = (unsigned short*)(ws + ETB_OFF);
    for (size_t x = i; x < (size_t)KK * NN; x += stride) {
        int k = (int)(x >> 11);
        int n = (int)(x & 2047);
        __hip_bfloat16 h = __float2bfloat16(enc[(size_t)n * KK + k]);
        Etb[x] = *(unsigned short*)&h;
    }
    for (size_t x = i; x < (size_t)B_ * DOUT; x += stride) out[x] = 0.0f;
}

// R7 skeleton (proven 3511 us): fence-free coalesced sc1 exchange, monotonic
// per-column counters, double-buffered ps, poll hidden behind the u-half of
// the encode. R9 change (encode ONLY): Et in bf16 (half bytes, half VMEM
// instrs), 4 neurons/lane b64 loads, wave-PAIR k-split so every load
// instruction covers ONE contiguous segment (R8's dual-segment instructions
// blew up L2 miss traffic 63x), cross-pair reduce via LDS Ap.
__global__ __launch_bounds__(THREADS, 2) void persist_kernel(
    const float* __restrict__ seq,            // [B][T][DIN]
    const unsigned short* __restrict__ Etb,   // [KK][NN] bf16
    const float* __restrict__ bias,
    const float* __restrict__ gain,
    const float* __restrict__ sd,    // [NN][DS]
    const float* __restrict__ dec,   // [NN][DOUT]
    float* __restrict__ ps,          // [2][BTILES][NTILES][BT][DS]
    unsigned int* __restrict__ bar,  // cnt[BTILES * 32]
    float* __restrict__ out)
{
    __shared__ float xs[BT][132];    // x_aug tile
    __shared__ float As[BT][516];    // activations [row][neuron]
    __shared__ float Ap[BT][516];    // cross-pair encode partials
    __shared__ float Dp[4][BT][65];  // decode cross-wave partials

    const int tid = threadIdx.x;
    const int nt = blockIdx.x & (NTILES - 1);
    const int bt = blockIdx.x >> 2;
    const int n0 = nt * NT;
    const int b0 = bt * BT;

    unsigned int* cnt = bar + (size_t)bt * 32;

    const int w  = tid >> 6;           // wave 0..3
    const int l  = tid & 63;
    const int pk = w >> 1;             // k-pair 0/1
    const int nb = (w & 1) * 256;      // neuron half
    const int nq = nb + 4 * l;         // 4 neurons/lane, contiguous per wave
    const int rs = tid >> 6;           // fan-in row
    const int cs = tid & 63;           // fan-in col

    // per-neuron params for the activation writers (waves 0,1)
    const float4 gg4 = *(const float4*)&gain[n0 + nq];
    const float4 bb4 = *(const float4*)&bias[n0 + nq];

    // unpack 4 bf16 (uint2) -> float4, exact (bit shift into high half)
#define BF2F4(qq) make_float4(                                   \
        __uint_as_float((qq).x << 16),                           \
        __uint_as_float((qq).x & 0xffff0000u),                   \
        __uint_as_float((qq).y << 16),                           \
        __uint_as_float((qq).y & 0xffff0000u))

    // 4 k-rows (kb..kb+3) x 4 neurons x 4 batch rows
#define ENC4(kb)                                                            \
    do {                                                                    \
        const unsigned short* ebp = &Etb[(size_t)(kb) * NN + n0 + nq];      \
        const uint2 q0 = *(const uint2*)(ebp);                              \
        const uint2 q1 = *(const uint2*)(ebp + NN);                         \
        const uint2 q2 = *(const uint2*)(ebp + 2 * (size_t)NN);             \
        const uint2 q3 = *(const uint2*)(ebp + 3 * (size_t)NN);             \
        const float4 e0 = BF2F4(q0);                                        \
        const float4 e1 = BF2F4(q1);                                        \
        const float4 e2 = BF2F4(q2);                                        \
        const float4 e3 = BF2F4(q3);                                        \
        const float4 x0 = *(const float4*)&xs[0][kb];                       \
        const float4 x1 = *(const float4*)&xs[1][kb];                       \
        const float4 x2 = *(const float4*)&xs[2][kb];                       \
        const float4 x3 = *(const float4*)&xs[3][kb];                       \
        acc0.x += e0.x*x0.x + e1.x*x0.y + e2.x*x0.z + e3.x*x0.w;            \
        acc0.y += e0.y*x0.x + e1.y*x0.y + e2.y*x0.z + e3.y*x0.w;            \
        acc0.z += e0.z*x0.x + e1.z*x0.y + e2.z*x0.z + e3.z*x0.w;            \
        acc0.w += e0.w*x0.x + e1.w*x0.y + e2.w*x0.z + e3.w*x0.w;            \
        acc1.x += e0.x*x1.x + e1.x*x1.y + e2.x*x1.z + e3.x*x1.w;            \
        acc1.y += e0.y*x1.x + e1.y*x1.y + e2.y*x1.z + e3.y*x1.w;            \
        acc1.z += e0.z*x1.x + e1.z*x1.y + e2.z*x1.z + e3.z*x1.w;            \
        acc1.w += e0.w*x1.x + e1.w*x1.y + e2.w*x1.z + e3.w*x1.w;            \
        acc2.x += e0.x*x2.x + e1.x*x2.y + e2.x*x2.z + e3.x*x2.w;            \
        acc2.y += e0.y*x2.x + e1.y*x2.y + e2.y*x2.z + e3.y*x2.w;            \
        acc2.z += e0.z*x2.x + e1.z*x2.y + e2.z*x2.z + e3.z*x2.w;            \
        acc2.w += e0.w*x2.x + e1.w*x2.y + e2.w*x2.z + e3.w*x2.w;            \
        acc3.x += e0.x*x3.x + e1.x*x3.y + e2.x*x3.z + e3.x*x3.w;            \
        acc3.y += e0.y*x3.x + e1.y*x3.y + e2.y*x3.z + e3.y*x3.w;            \
        acc3.z += e0.z*x3.x + e1.z*x3.y + e2.z*x3.z + e3.z*x3.w;            \
        acc3.w += e0.w*x3.x + e1.w*x3.y + e2.w*x3.z + e3.w*x3.w;            \
    } while (0)

    for (int t = 0; t < T_; ++t) {
        // ---- stage u_t into xs[.][0..63] (R7 verbatim) ----
        if (tid < 64) {
            const int r = tid >> 4, c = (tid & 15) << 2;
            *(float4*)&xs[r][c] =
                *(const float4*)&seq[((size_t)(b0 + r) * T_ + t) * DIN + c];
        }
        __syncthreads();

        // ---- encode PASS A (u-half): pair pk covers k in [pk*32, pk*32+32) ----
        float4 acc0 = {0,0,0,0}, acc1 = {0,0,0,0}, acc2 = {0,0,0,0}, acc3 = {0,0,0,0};
        {
            const int ka = pk * 32;
            #pragma unroll
            for (int i = 0; i < 8; ++i) ENC4(ka + 4 * i);
        }

        // ---- acquire state s(t-1): poll + coalesced sc1 fan-in (R7 verbatim) ----
        if (t > 0) {
            if (tid == 0) {
                while (__hip_atomic_load(cnt, __ATOMIC_RELAXED, __HIP_MEMORY_SCOPE_AGENT)
                       < 4u * (unsigned)t)
                    __builtin_amdgcn_s_sleep(1);
            }
            __syncthreads();
            const float* pb = ps + (size_t)((t - 1) & 1) * PS1;
            float ssum = 0.f;
            #pragma unroll
            for (int p = 0; p < NTILES; ++p)
                ssum += __hip_atomic_load(
                    pb + (((size_t)bt * NTILES + p) * BT + rs) * DS + cs,
                    __ATOMIC_RELAXED, __HIP_MEMORY_SCOPE_AGENT);
            xs[rs][DIN + cs] = ssum;
        } else {
            xs[rs][DIN + cs] = 0.f;
        }
        __syncthreads();

        // ---- encode PASS B (s-half): k in [64+pk*32, 64+pk*32+32) ----
        {
            const int kb0 = 64 + pk * 32;
            #pragma unroll
            for (int i = 0; i < 8; ++i) ENC4(kb0 + 4 * i);
        }

        // ---- cross-pair reduce via LDS: pair 1 publishes, pair 0 finishes ----
        if (w >= 2) {
            *(float4*)&Ap[0][nq] = acc0;
            *(float4*)&Ap[1][nq] = acc1;
            *(float4*)&Ap[2][nq] = acc2;
            *(float4*)&Ap[3][nq] = acc3;
        }
        __syncthreads();
        if (w < 2) {
            const float4 p0 = *(const float4*)&Ap[0][nq];
            const float4 p1 = *(const float4*)&Ap[1][nq];
            const float4 p2 = *(const float4*)&Ap[2][nq];
            const float4 p3 = *(const float4*)&Ap[3][nq];
            float4 v;
            v.x = fabsf(gg4.x*(acc0.x+p0.x) + bb4.x);
            v.y = fabsf(gg4.y*(acc0.y+p0.y) + bb4.y);
            v.z = fabsf(gg4.z*(acc0.z+p0.z) + bb4.z);
            v.w = fabsf(gg4.w*(acc0.w+p0.w) + bb4.w);
            *(float4*)&As[0][nq] = v;
            v.x = fabsf(gg4.x*(acc1.x+p1.x) + bb4.x);
            v.y = fabsf(gg4.y*(acc1.y+p1.y) + bb4.y);
            v.z = fabsf(gg4.z*(acc1.z+p1.z) + bb4.z);
            v.w = fabsf(gg4.w*(acc1.w+p1.w) + bb4.w);
            *(float4*)&As[1][nq] = v;
            v.x = fabsf(gg4.x*(acc2.x+p2.x) + bb4.x);
            v.y = fabsf(gg4.y*(acc2.y+p2.y) + bb4.y);
            v.z = fabsf(gg4.z*(acc2.z+p2.z) + bb4.z);
            v.w = fabsf(gg4.w*(acc2.w+p2.w) + bb4.w);
            *(float4*)&As[2][nq] = v;
            v.x = fabsf(gg4.x*(acc3.x+p3.x) + bb4.x);
            v.y = fabsf(gg4.y*(acc3.y+p3.y) + bb4.y);
            v.z = fabsf(gg4.z*(acc3.z+p3.z) + bb4.z);
            v.w = fabsf(gg4.w*(acc3.w+p3.w) + bb4.w);
            *(float4*)&As[3][nq] = v;
        }
        __syncthreads();

        if (t == T_ - 1) {
            // ---- final projection: out += A_tile @ dec_tile (R7 verbatim) ----
            for (int idx = tid; idx < BT * DOUT; idx += THREADS) {
                const int r = idx / DOUT;
                const int d = idx % DOUT;
                float o = 0.f;
                #pragma unroll 8
                for (int n = 0; n < NT; ++n)
                    o += As[r][n] * dec[(size_t)(n0 + n) * DOUT + d];
                atomicAdd(&out[(size_t)(b0 + r) * DOUT + d], o);
            }
            return;
        }

        // ---- decode (R7 verbatim): wave w sums n-range [w*128, +128) ----
        {
            float d0 = 0.f, d1 = 0.f, d2 = 0.f, d3 = 0.f;
            const int nb0 = w * 128;
            #pragma unroll 8
            for (int n = 0; n < 128; ++n) {
                const float sv = sd[(size_t)(n0 + nb0 + n) * DS + l];  // coalesced b32
                const float av0 = As[0][nb0 + n];   // LDS broadcast
                const float av1 = As[1][nb0 + n];
                const float av2 = As[2][nb0 + n];
                const float av3 = As[3][nb0 + n];
                d0 += av0 * sv; d1 += av1 * sv; d2 += av2 * sv; d3 += av3 * sv;
            }
            if (w > 0) {
                Dp[w][0][l] = d0; Dp[w][1][l] = d1;
                Dp[w][2][l] = d2; Dp[w][3][l] = d3;
            }
            __syncthreads();
            if (w == 0) {
                #pragma unroll
                for (int p = 1; p < 4; ++p) {
                    d0 += Dp[p][0][l]; d1 += Dp[p][1][l];
                    d2 += Dp[p][2][l]; d3 += Dp[p][3][l];
                }
                float* pw = ps + (size_t)(t & 1) * PS1
                               + (((size_t)bt * NTILES + nt) * BT) * DS + l;
                __hip_atomic_store(pw + 0*DS, d0, __ATOMIC_RELAXED, __HIP_MEMORY_SCOPE_AGENT);
                __hip_atomic_store(pw + 1*DS, d1, __ATOMIC_RELAXED, __HIP_MEMORY_SCOPE_AGENT);
                __hip_atomic_store(pw + 2*DS, d2, __ATOMIC_RELAXED, __HIP_MEMORY_SCOPE_AGENT);
                __hip_atomic_store(pw + 3*DS, d3, __ATOMIC_RELAXED, __HIP_MEMORY_SCOPE_AGENT);
            }
        }

        // ---- arrive: drain sc1 stores, bump generation (R7 verbatim) ----
        asm volatile("s_waitcnt vmcnt(0)" ::: "memory");
        __syncthreads();
        if (tid == 0)
            __hip_atomic_fetch_add(cnt, 1u, __ATOMIC_RELAXED, __HIP_MEMORY_SCOPE_AGENT);
    }
#undef ENC4
#undef BF2F4
}

extern "C" void kernel_launch(void* const* d_in, const int* in_sizes, int n_in,
                              void* d_out, int out_size, void* d_ws, size_t ws_size,
                              hipStream_t stream) {
    const float* seq  = (const float*)d_in[0];
    const float* enc  = (const float*)d_in[1];
    const float* bias = (const float*)d_in[2];
    const float* gain = (const float*)d_in[3];
    const float* sd   = (const float*)d_in[4];
    const float* dec  = (const float*)d_in[5];
    float* out = (float*)d_out;
    float* ws  = (float*)d_ws;   // ps[2] | Etb | counters  (~1.6 MB)

    pre_kernel<<<dim3(1024), dim3(256), 0, stream>>>(enc, ws, out);

    float* ps = ws;
    const unsigned short* Etb = (const unsigned short*)(ws + ETB_OFF);
    unsigned int* bar = (unsigned int*)(ws + BAR_OFF);

    persist_kernel<<<dim3(NWG), dim3(THREADS), 0, stream>>>(
        seq, Etb, bias, gain, sd, dec, ps, bar, out);
}

// Round 10
// 4819.974 us; speedup vs baseline: 4.2597x; 4.2597x over previous
//
#include <hip/hip_runtime.h>
#include <hip/hip_bf16.h>
#include <math.h>

// Problem constants
#define B_    512
#define T_    256
#define DIN   64
#define DS    64
#define KK    128   // DIN + DS
#define NN    2048
#define DOUT  10

// Tiling: 512 WGs = NTILES(4) x BTILES(128), 256 thr, 2 WG/CU.
#define NT      512
#define BT      4
#define NTILES  (NN / NT)      // 4
#define BTILES  (B_ / BT)      // 128
#define THREADS 256
#define NWG     (NTILES * BTILES)   // 512

// Workspace (float offsets): ps double-buffer | Etb (bf16) | counters
#define PS1        ((size_t)BTILES * NTILES * BT * DS)   // 131072 floats (512 KB)
#define PS_TOT     (2 * PS1)
#define ETB_OFF    PS_TOT
#define ETB_FLOATS ((size_t)KK * NN / 2)                 // bf16 Et = 512 KB
#define BAR_OFF    (ETB_OFF + ETB_FLOATS)
#define BAR_UINTS  4096

__global__ __launch_bounds__(256) void pre_kernel(const float* __restrict__ enc,
                                                  float* __restrict__ ws,
                                                  float* __restrict__ out) {
    size_t i = (size_t)blockIdx.x * blockDim.x + threadIdx.x;
    size_t stride = (size_t)gridDim.x * blockDim.x;
    unsigned int* bar = (unsigned int*)(ws + BAR_OFF);
    for (size_t x = i; x < BAR_UINTS; x += stride) bar[x] = 0u;
    // Etb[k][n] = bf16_rn(enc[n][k])
    unsigned short* Etb = (unsigned short*)(ws + ETB_OFF);
    for (size_t x = i; x < (size_t)KK * NN; x += stride) {
        int k = (int)(x >> 11);
        int n = (int)(x & 2047);
        __hip_bfloat16 h = __float2bfloat16(enc[(size_t)n * KK + k]);
        Etb[x] = *(unsigned short*)&h;
    }
    for (size_t x = i; x < (size_t)B_ * DOUT; x += stride) out[x] = 0.0f;
}

// EXACT R7 kernel (proven 3511 us: fence-free coalesced sc1 exchange,
// monotonic per-column counters, double-buffered ps, poll hidden behind the
// u-half of the encode, wave-per-128-neurons decode). ONE change: Et is bf16,
// loaded as uint (2 neurons, 4 B/lane, same lane mapping / segment shape as
// R7's float2) and unpacked with shift/mask. Halves encode L2 bytes; LOWERS
// register pressure (R8/R9 regressions were VGPR-128 spill -> scratch traffic
// -> L2 thrash; WRITE_SIZE 9.7 GB was the tell).
__global__ __launch_bounds__(THREADS, 2) void persist_kernel(
    const float* __restrict__ seq,            // [B][T][DIN]
    const unsigned short* __restrict__ Etb,   // [KK][NN] bf16
    const float* __restrict__ bias,
    const float* __restrict__ gain,
    const float* __restrict__ sd,    // [NN][DS]
    const float* __restrict__ dec,   // [NN][DOUT]
    float* __restrict__ ps,          // [2][BTILES][NTILES][BT][DS]
    unsigned int* __restrict__ bar,  // cnt[BTILES * 32]
    float* __restrict__ out)
{
    __shared__ float xs[BT][132];    // x_aug tile
    __shared__ float As[BT][516];    // activations [row][neuron 0..511]
    __shared__ float Dp[4][4][65];   // decode cross-wave partials

    const int tid = threadIdx.x;
    const int nt = blockIdx.x & (NTILES - 1);
    const int bt = blockIdx.x >> 2;
    const int n0 = nt * NT;
    const int b0 = bt * BT;

    unsigned int* cnt = bar + (size_t)bt * 32;

    const int w = tid >> 6;            // wave 0..3
    const int l = tid & 63;            // lane
    const int nl = w * 128 + 2 * l;    // encode: local neuron pair base
    const int rs = tid >> 6;           // s-exchange row 0..3
    const int cs = tid & 63;           // s-exchange col 0..63

    // loop-invariant per-neuron params (2 neurons/lane)
    const float2 gg = *(const float2*)&gain[n0 + nl];
    const float2 bb = *(const float2*)&bias[n0 + nl];

    // one uint = 2 bf16 neurons; unpack exact (shift into fp32 high bits)
#define LDE(e, kk)                                                          \
    float2 e;                                                               \
    {                                                                       \
        const unsigned int u_ = *(const unsigned int*)&Etb[(size_t)(kk) * NN + n0 + nl]; \
        e.x = __uint_as_float(u_ << 16);                                    \
        e.y = __uint_as_float(u_ & 0xffff0000u);                            \
    }

    for (int t = 0; t < T_; ++t) {
        // ---- stage u_t into xs[.][0..63] ----
        if (tid < 64) {
            const int r = tid >> 4, c = (tid & 15) << 2;
            *(float4*)&xs[r][c] =
                *(const float4*)&seq[((size_t)(b0 + r) * T_ + t) * DIN + c];
        }
        __syncthreads();

        // ---- encode U-half: k = 0..63 (state-independent, hides the poll) ----
        float2 a0 = {0.f,0.f}, a1 = {0.f,0.f}, a2 = {0.f,0.f}, a3 = {0.f,0.f};
        #pragma unroll 4
        for (int k = 0; k < 64; k += 4) {
            LDE(e0, k+0) LDE(e1, k+1) LDE(e2, k+2) LDE(e3, k+3)
            const float4 x0 = *(const float4*)&xs[0][k];
            const float4 x1 = *(const float4*)&xs[1][k];
            const float4 x2 = *(const float4*)&xs[2][k];
            const float4 x3 = *(const float4*)&xs[3][k];
            a0.x += e0.x*x0.x + e1.x*x0.y + e2.x*x0.z + e3.x*x0.w;
            a0.y += e0.y*x0.x + e1.y*x0.y + e2.y*x0.z + e3.y*x0.w;
            a1.x += e0.x*x1.x + e1.x*x1.y + e2.x*x1.z + e3.x*x1.w;
            a1.y += e0.y*x1.x + e1.y*x1.y + e2.y*x1.z + e3.y*x1.w;
            a2.x += e0.x*x2.x + e1.x*x2.y + e2.x*x2.z + e3.x*x2.w;
            a2.y += e0.y*x2.x + e1.y*x2.y + e2.y*x2.z + e3.y*x2.w;
            a3.x += e0.x*x3.x + e1.x*x3.y + e2.x*x3.z + e3.x*x3.w;
            a3.y += e0.y*x3.x + e1.y*x3.y + e2.y*x3.z + e3.y*x3.w;
        }

        // ---- acquire state s(t-1): poll + coalesced sc1 fan-in (4 partials) ----
        if (t > 0) {
            if (tid == 0) {
                while (__hip_atomic_load(cnt, __ATOMIC_RELAXED, __HIP_MEMORY_SCOPE_AGENT)
                       < 4u * (unsigned)t)
                    __builtin_amdgcn_s_sleep(1);
            }
            __syncthreads();
            const float* pb = ps + (size_t)((t - 1) & 1) * PS1;
            float ssum = 0.f;
            #pragma unroll
            for (int p = 0; p < NTILES; ++p)
                ssum += __hip_atomic_load(
                    pb + (((size_t)bt * NTILES + p) * BT + rs) * DS + cs,
                    __ATOMIC_RELAXED, __HIP_MEMORY_SCOPE_AGENT);
            xs[rs][DIN + cs] = ssum;
        } else {
            xs[rs][DIN + cs] = 0.f;
        }
        __syncthreads();

        // ---- encode S-half: k = 64..127 ----
        #pragma unroll 4
        for (int k = 64; k < 128; k += 4) {
            LDE(e0, k+0) LDE(e1, k+1) LDE(e2, k+2) LDE(e3, k+3)
            const float4 x0 = *(const float4*)&xs[0][k];
            const float4 x1 = *(const float4*)&xs[1][k];
            const float4 x2 = *(const float4*)&xs[2][k];
            const float4 x3 = *(const float4*)&xs[3][k];
            a0.x += e0.x*x0.x + e1.x*x0.y + e2.x*x0.z + e3.x*x0.w;
            a0.y += e0.y*x0.x + e1.y*x0.y + e2.y*x0.z + e3.y*x0.w;
            a1.x += e0.x*x1.x + e1.x*x1.y + e2.x*x1.z + e3.x*x1.w;
            a1.y += e0.y*x1.x + e1.y*x1.y + e2.y*x1.z + e3.y*x1.w;
            a2.x += e0.x*x2.x + e1.x*x2.y + e2.x*x2.z + e3.x*x2.w;
            a2.y += e0.y*x2.x + e1.y*x2.y + e2.y*x2.z + e3.y*x2.w;
            a3.x += e0.x*x3.x + e1.x*x3.y + e2.x*x3.z + e3.x*x3.w;
            a3.y += e0.y*x3.x + e1.y*x3.y + e2.y*x3.z + e3.y*x3.w;
        }

        // ---- activation -> As ----
        {
            float2 v;
            v.x = fabsf(gg.x*a0.x + bb.x); v.y = fabsf(gg.y*a0.y + bb.y);
            *(float2*)&As[0][nl] = v;
            v.x = fabsf(gg.x*a1.x + bb.x); v.y = fabsf(gg.y*a1.y + bb.y);
            *(float2*)&As[1][nl] = v;
            v.x = fabsf(gg.x*a2.x + bb.x); v.y = fabsf(gg.y*a2.y + bb.y);
            *(float2*)&As[2][nl] = v;
            v.x = fabsf(gg.x*a3.x + bb.x); v.y = fabsf(gg.y*a3.y + bb.y);
            *(float2*)&As[3][nl] = v;
        }
        __syncthreads();

        if (t == T_ - 1) {
            // ---- final projection: out += A_tile @ dec_tile ----
            for (int idx = tid; idx < BT * DOUT; idx += THREADS) {
                const int r = idx / DOUT;
                const int d = idx % DOUT;
                float o = 0.f;
                #pragma unroll 8
                for (int n = 0; n < NT; ++n)
                    o += As[r][n] * dec[(size_t)(n0 + n) * DOUT + d];
                atomicAdd(&out[(size_t)(b0 + r) * DOUT + d], o);
            }
            return;
        }

        // ---- decode: wave w sums n-range [w*128, w*128+128), lane = state col ----
        {
            float d0 = 0.f, d1 = 0.f, d2 = 0.f, d3 = 0.f;
            const int nb0 = w * 128;
            #pragma unroll 8
            for (int n = 0; n < 128; ++n) {
                const float sv = sd[(size_t)(n0 + nb0 + n) * DS + l];  // coalesced b32
                const float av0 = As[0][nb0 + n];   // LDS broadcast
                const float av1 = As[1][nb0 + n];
                const float av2 = As[2][nb0 + n];
                const float av3 = As[3][nb0 + n];
                d0 += av0 * sv; d1 += av1 * sv; d2 += av2 * sv; d3 += av3 * sv;
            }
            if (w > 0) {
                Dp[w][0][l] = d0; Dp[w][1][l] = d1;
                Dp[w][2][l] = d2; Dp[w][3][l] = d3;
            }
            __syncthreads();
            if (w == 0) {
                #pragma unroll
                for (int p = 1; p < 4; ++p) {
                    d0 += Dp[p][0][l]; d1 += Dp[p][1][l];
                    d2 += Dp[p][2][l]; d3 += Dp[p][3][l];
                }
                // write this WG's partial: ps[t&1][bt][nt][r][l], coalesced sc1
                float* pw = ps + (size_t)(t & 1) * PS1
                               + (((size_t)bt * NTILES + nt) * BT) * DS + l;
                __hip_atomic_store(pw + 0*DS, d0, __ATOMIC_RELAXED, __HIP_MEMORY_SCOPE_AGENT);
                __hip_atomic_store(pw + 1*DS, d1, __ATOMIC_RELAXED, __HIP_MEMORY_SCOPE_AGENT);
                __hip_atomic_store(pw + 2*DS, d2, __ATOMIC_RELAXED, __HIP_MEMORY_SCOPE_AGENT);
                __hip_atomic_store(pw + 3*DS, d3, __ATOMIC_RELAXED, __HIP_MEMORY_SCOPE_AGENT);
            }
        }

        // ---- arrive: drain sc1 stores, bump generation ----
        asm volatile("s_waitcnt vmcnt(0)" ::: "memory");
        __syncthreads();
        if (tid == 0)
            __hip_atomic_fetch_add(cnt, 1u, __ATOMIC_RELAXED, __HIP_MEMORY_SCOPE_AGENT);
    }
#undef LDE
}

extern "C" void kernel_launch(void* const* d_in, const int* in_sizes, int n_in,
                              void* d_out, int out_size, void* d_ws, size_t ws_size,
                              hipStream_t stream) {
    const float* seq  = (const float*)d_in[0];
    const float* enc  = (const float*)d_in[1];
    const float* bias = (const float*)d_in[2];
    const float* gain = (const float*)d_in[3];
    const float* sd   = (const float*)d_in[4];
    const float* dec  = (const float*)d_in[5];
    float* out = (float*)d_out;
    float* ws  = (float*)d_ws;   // ps[2] | Etb | counters  (~1.6 MB)

    pre_kernel<<<dim3(1024), dim3(256), 0, stream>>>(enc, ws, out);

    float* ps = ws;
    const unsigned short* Etb = (const unsigned short*)(ws + ETB_OFF);
    unsigned int* bar = (unsigned int*)(ws + BAR_OFF);

    persist_kernel<<<dim3(NWG), dim3(THREADS), 0, stream>>>(
        seq, Etb, bias, gain, sd, dec, ps, bar, out);
}

// Round 11
// 1797.199 us; speedup vs baseline: 11.4242x; 2.6819x over previous
//
#include <hip/hip_runtime.h>
#include <math.h>

// Problem constants
#define B_    512
#define T_    256
#define DIN   64
#define DS    64
#define KK    128   // DIN + DS
#define NN    2048
#define DOUT  10

// Tiling: 512 WGs = NTILES(4) x BTILES(128), 256 thr, 2 WG/CU.
#define NT      512
#define BT      4
#define NTILES  (NN / NT)      // 4
#define BTILES  (B_ / BT)      // 128
#define THREADS 256
#define NWG     (NTILES * BTILES)   // 512

// Workspace (float offsets): ps double-buffer | EtSw (f16, B-frag order) | counters
#define PS1        ((size_t)BTILES * NTILES * BT * DS)   // 131072 floats (512 KB)
#define PS_TOT     (2 * PS1)
#define ETSW_OFF   PS_TOT
#define ETSW_F16   ((size_t)KK * NN)                     // 262144 f16 = 512 KB
#define BAR_OFF    (ETSW_OFF + ETSW_F16 / 2)
#define BAR_UINTS  4096

typedef _Float16 half8 __attribute__((ext_vector_type(8)));
typedef float    f32x4 __attribute__((ext_vector_type(4)));

__global__ __launch_bounds__(256) void pre_kernel(const float* __restrict__ enc,
                                                  float* __restrict__ ws,
                                                  float* __restrict__ out) {
    size_t i = (size_t)blockIdx.x * blockDim.x + threadIdx.x;
    size_t stride = (size_t)gridDim.x * blockDim.x;
    unsigned int* bar = (unsigned int*)(ws + BAR_OFF);
    for (size_t x = i; x < BAR_UINTS; x += stride) bar[x] = 0u;
    // EtSw: B-fragment order for mfma_f32_16x16x32_f16.
    // x = ((((ntq*4 + w)*8 + ntile)*4 + ktile)*64 + lane)*8 + j
    // n = ntq*512 + w*128 + ntile*16 + (lane&15); k = ktile*32 + (lane>>4)*8 + j
    _Float16* EtSw = (_Float16*)(ws + ETSW_OFF);
    for (size_t x = i; x < (size_t)KK * NN; x += stride) {
        const int j     = (int)(x & 7);
        const int lane  = (int)((x >> 3) & 63);
        const int ktile = (int)((x >> 9) & 3);
        const int ntile = (int)((x >> 11) & 7);
        const int w     = (int)((x >> 14) & 3);
        const int ntq   = (int)(x >> 16);
        const int n = ntq * 512 + w * 128 + ntile * 16 + (lane & 15);
        const int k = ktile * 32 + ((lane >> 4) << 3) + j;
        EtSw[x] = (_Float16)enc[(size_t)n * KK + k];
    }
    for (size_t x = i; x < (size_t)B_ * DOUT; x += stride) out[x] = 0.0f;
}

// R7 skeleton (proven 3511 us): fence-free coalesced sc1 exchange, monotonic
// per-column counters, double-buffered fp32 ps, poll hidden mid-encode,
// wave-per-128-neurons VALU decode — all byte-identical. R11 change: encode
// GEMM on MFMA f16 (M=16, rows 4..15 zero-padded). B-frags pre-swizzled in
// global (coalesced b128), A-frags from f16 LDS xh[16][136] (pad => <=2-way
// conflicts, free). k-tiles 0-1 pre-poll, 2-3 post-poll.
__global__ __launch_bounds__(THREADS, 2) void persist_kernel(
    const float* __restrict__ seq,          // [B][T][DIN]
    const _Float16* __restrict__ EtSw,      // swizzled encoder fragments
    const float* __restrict__ bias,
    const float* __restrict__ gain,
    const float* __restrict__ sd,    // [NN][DS]
    const float* __restrict__ dec,   // [NN][DOUT]
    float* __restrict__ ps,          // [2][BTILES][NTILES][BT][DS]
    unsigned int* __restrict__ bar,  // cnt[BTILES * 32]
    float* __restrict__ out)
{
    __shared__ _Float16 xh[16][136]; // x_aug f16, rows 4..15 zero (A-operand)
    __shared__ float As[BT][516];    // activations [row][neuron 0..511]
    __shared__ float Dp[4][4][65];   // decode cross-wave partials

    const int tid = threadIdx.x;
    const int nt = blockIdx.x & (NTILES - 1);
    const int bt = blockIdx.x >> 2;
    const int n0 = nt * NT;
    const int b0 = bt * BT;

    unsigned int* cnt = bar + (size_t)bt * 32;

    const int w = tid >> 6;            // wave 0..3
    const int l = tid & 63;            // lane
    const int rs = tid >> 6;           // s-exchange row 0..3
    const int cs = tid & 63;           // s-exchange col 0..63
    const int m16 = l & 15;            // fragment row/col index
    const int q8  = (l >> 4) << 3;     // fragment k sub-offset

    // per-wave swizzled-weight base: [ntile 8][ktile 4][lane 64][8]
    const _Float16* EtW = EtSw + ((size_t)(nt * 4 + w) << 14);

    // loop-invariant epilogue params (lanes 0..15 use them)
    float gv[8], bv[8];
    #pragma unroll
    for (int n8 = 0; n8 < 8; ++n8) {
        gv[n8] = gain[n0 + w * 128 + n8 * 16 + m16];
        bv[n8] = bias[n0 + w * 128 + n8 * 16 + m16];
    }

    // zero xh once (rows 4..15 stay zero forever; rows 0..3 rewritten per step)
    {
        unsigned int* xz = (unsigned int*)&xh[0][0];
        for (int i2 = tid; i2 < 16 * 136 / 2; i2 += THREADS) xz[i2] = 0u;
    }
    __syncthreads();

    for (int t = 0; t < T_; ++t) {
        // ---- stage u_t into xh rows 0..3, k 0..63 ----
        if (tid < 64) {
            const int r = tid >> 4, c = (tid & 15) << 2;
            const float4 uv = *(const float4*)&seq[((size_t)(b0 + r) * T_ + t) * DIN + c];
            _Float16* p = &xh[r][c];
            p[0] = (_Float16)uv.x; p[1] = (_Float16)uv.y;
            p[2] = (_Float16)uv.z; p[3] = (_Float16)uv.w;
        }
        __syncthreads();

        // ---- encode phase A: k-tiles 0,1 (input half) over 8 n-tiles ----
        f32x4 acc[8];
        #pragma unroll
        for (int n8 = 0; n8 < 8; ++n8) acc[n8] = (f32x4){0.f, 0.f, 0.f, 0.f};
        {
            const half8 af0 = *(const half8*)&xh[m16][q8];
            const half8 af1 = *(const half8*)&xh[m16][32 + q8];
            #pragma unroll
            for (int n8 = 0; n8 < 8; ++n8) {
                const half8 b0 = *(const half8*)&EtW[(n8 << 11) + (size_t)l * 8];
                const half8 b1 = *(const half8*)&EtW[(n8 << 11) + (1 << 9) + (size_t)l * 8];
                acc[n8] = __builtin_amdgcn_mfma_f32_16x16x32_f16(af0, b0, acc[n8], 0, 0, 0);
                acc[n8] = __builtin_amdgcn_mfma_f32_16x16x32_f16(af1, b1, acc[n8], 0, 0, 0);
            }
        }

        // ---- acquire state s(t-1): poll + coalesced sc1 fan-in (R7 verbatim) ----
        if (t > 0) {
            if (tid == 0) {
                while (__hip_atomic_load(cnt, __ATOMIC_RELAXED, __HIP_MEMORY_SCOPE_AGENT)
                       < 4u * (unsigned)t)
                    __builtin_amdgcn_s_sleep(1);
            }
            __syncthreads();
            const float* pb = ps + (size_t)((t - 1) & 1) * PS1;
            float ssum = 0.f;
            #pragma unroll
            for (int p = 0; p < NTILES; ++p)
                ssum += __hip_atomic_load(
                    pb + (((size_t)bt * NTILES + p) * BT + rs) * DS + cs,
                    __ATOMIC_RELAXED, __HIP_MEMORY_SCOPE_AGENT);
            xh[rs][DIN + cs] = (_Float16)ssum;
        } else {
            xh[rs][DIN + cs] = (_Float16)0.f;
        }
        __syncthreads();

        // ---- encode phase B: k-tiles 2,3 (state half) ----
        {
            const half8 af2 = *(const half8*)&xh[m16][64 + q8];
            const half8 af3 = *(const half8*)&xh[m16][96 + q8];
            #pragma unroll
            for (int n8 = 0; n8 < 8; ++n8) {
                const half8 b2 = *(const half8*)&EtW[(n8 << 11) + (2 << 9) + (size_t)l * 8];
                const half8 b3 = *(const half8*)&EtW[(n8 << 11) + (3 << 9) + (size_t)l * 8];
                acc[n8] = __builtin_amdgcn_mfma_f32_16x16x32_f16(af2, b2, acc[n8], 0, 0, 0);
                acc[n8] = __builtin_amdgcn_mfma_f32_16x16x32_f16(af3, b3, acc[n8], 0, 0, 0);
            }
        }

        // ---- epilogue: C/D col=lane&15, row=quad*4+reg -> lanes 0..15 hold rows 0..3 ----
        if (l < 16) {
            #pragma unroll
            for (int n8 = 0; n8 < 8; ++n8) {
                const int n = w * 128 + n8 * 16 + m16;
                As[0][n] = fabsf(gv[n8] * acc[n8][0] + bv[n8]);
                As[1][n] = fabsf(gv[n8] * acc[n8][1] + bv[n8]);
                As[2][n] = fabsf(gv[n8] * acc[n8][2] + bv[n8]);
                As[3][n] = fabsf(gv[n8] * acc[n8][3] + bv[n8]);
            }
        }
        __syncthreads();

        if (t == T_ - 1) {
            // ---- final projection: out += A_tile @ dec_tile (R7 verbatim) ----
            for (int idx = tid; idx < BT * DOUT; idx += THREADS) {
                const int r = idx / DOUT;
                const int d = idx % DOUT;
                float o = 0.f;
                #pragma unroll 8
                for (int n = 0; n < NT; ++n)
                    o += As[r][n] * dec[(size_t)(n0 + n) * DOUT + d];
                atomicAdd(&out[(size_t)(b0 + r) * DOUT + d], o);
            }
            return;
        }

        // ---- decode (R7 verbatim): wave w sums n-range [w*128, +128) ----
        {
            float d0 = 0.f, d1 = 0.f, d2 = 0.f, d3 = 0.f;
            const int nb0 = w * 128;
            #pragma unroll 8
            for (int n = 0; n < 128; ++n) {
                const float sv = sd[(size_t)(n0 + nb0 + n) * DS + l];  // coalesced b32
                const float av0 = As[0][nb0 + n];   // LDS broadcast
                const float av1 = As[1][nb0 + n];
                const float av2 = As[2][nb0 + n];
                const float av3 = As[3][nb0 + n];
                d0 += av0 * sv; d1 += av1 * sv; d2 += av2 * sv; d3 += av3 * sv;
            }
            if (w > 0) {
                Dp[w][0][l] = d0; Dp[w][1][l] = d1;
                Dp[w][2][l] = d2; Dp[w][3][l] = d3;
            }
            __syncthreads();
            if (w == 0) {
                #pragma unroll
                for (int p = 1; p < 4; ++p) {
                    d0 += Dp[p][0][l]; d1 += Dp[p][1][l];
                    d2 += Dp[p][2][l]; d3 += Dp[p][3][l];
                }
                float* pw = ps + (size_t)(t & 1) * PS1
                               + (((size_t)bt * NTILES + nt) * BT) * DS + l;
                __hip_atomic_store(pw + 0*DS, d0, __ATOMIC_RELAXED, __HIP_MEMORY_SCOPE_AGENT);
                __hip_atomic_store(pw + 1*DS, d1, __ATOMIC_RELAXED, __HIP_MEMORY_SCOPE_AGENT);
                __hip_atomic_store(pw + 2*DS, d2, __ATOMIC_RELAXED, __HIP_MEMORY_SCOPE_AGENT);
                __hip_atomic_store(pw + 3*DS, d3, __ATOMIC_RELAXED, __HIP_MEMORY_SCOPE_AGENT);
            }
        }

        // ---- arrive: drain sc1 stores, bump generation (R7 verbatim) ----
        asm volatile("s_waitcnt vmcnt(0)" ::: "memory");
        __syncthreads();
        if (tid == 0)
            __hip_atomic_fetch_add(cnt, 1u, __ATOMIC_RELAXED, __HIP_MEMORY_SCOPE_AGENT);
    }
}

extern "C" void kernel_launch(void* const* d_in, const int* in_sizes, int n_in,
                              void* d_out, int out_size, void* d_ws, size_t ws_size,
                              hipStream_t stream) {
    const float* seq  = (const float*)d_in[0];
    const float* enc  = (const float*)d_in[1];
    const float* bias = (const float*)d_in[2];
    const float* gain = (const float*)d_in[3];
    const float* sd   = (const float*)d_in[4];
    const float* dec  = (const float*)d_in[5];
    float* out = (float*)d_out;
    float* ws  = (float*)d_ws;   // ps[2] | EtSw | counters  (~1.6 MB)

    pre_kernel<<<dim3(1024), dim3(256), 0, stream>>>(enc, ws, out);

    float* ps = ws;
    const _Float16* EtSw = (const _Float16*)(ws + ETSW_OFF);
    unsigned int* bar = (unsigned int*)(ws + BAR_OFF);

    persist_kernel<<<dim3(NWG), dim3(THREADS), 0, stream>>>(
        seq, EtSw, bias, gain, sd, dec, ps, bar, out);
}

// Round 12
// 1239.832 us; speedup vs baseline: 16.5600x; 1.4496x over previous
//
#include <hip/hip_runtime.h>
#include <math.h>

// Problem constants
#define B_    512
#define T_    256
#define DIN   64
#define DS    64
#define KK    128   // DIN + DS
#define NN    2048
#define DOUT  10

// Tiling: 512 WGs = NTILES(4) x BTILES(128), 256 thr, 2 WG/CU.
#define NT      512
#define BT      4
#define NTILES  (NN / NT)      // 4
#define BTILES  (B_ / BT)      // 128
#define THREADS 256
#define NWG     (NTILES * BTILES)   // 512

// Workspace (float offsets): ps[2] | EtSw (f16 B-frags) | SdSw (f16 B-frags) | counters
#define PS1        ((size_t)BTILES * NTILES * BT * DS)   // 131072 floats (512 KB)
#define PS_TOT     (2 * PS1)
#define ETSW_OFF   PS_TOT
#define ETSW_F16   ((size_t)KK * NN)                     // 262144 f16 = 512 KB
#define SDSW_OFF   (ETSW_OFF + ETSW_F16 / 2)
#define SDSW_F16   ((size_t)NN * DS)                     // 131072 f16 = 256 KB
#define BAR_OFF    (SDSW_OFF + SDSW_F16 / 2)
#define BAR_UINTS  4096

typedef _Float16 half8 __attribute__((ext_vector_type(8)));
typedef float    f32x4 __attribute__((ext_vector_type(4)));

__global__ __launch_bounds__(256) void pre_kernel(const float* __restrict__ enc,
                                                  const float* __restrict__ sd,
                                                  float* __restrict__ ws,
                                                  float* __restrict__ out) {
    size_t i = (size_t)blockIdx.x * blockDim.x + threadIdx.x;
    size_t stride = (size_t)gridDim.x * blockDim.x;
    unsigned int* bar = (unsigned int*)(ws + BAR_OFF);
    for (size_t x = i; x < BAR_UINTS; x += stride) bar[x] = 0u;
    // EtSw: B-fragment order for mfma_f32_16x16x32_f16 (R11-verified).
    _Float16* EtSw = (_Float16*)(ws + ETSW_OFF);
    for (size_t x = i; x < (size_t)KK * NN; x += stride) {
        const int j     = (int)(x & 7);
        const int lane  = (int)((x >> 3) & 63);
        const int ktile = (int)((x >> 9) & 3);
        const int ntile = (int)((x >> 11) & 7);
        const int w     = (int)((x >> 14) & 3);
        const int ntq   = (int)(x >> 16);
        const int n = ntq * 512 + w * 128 + ntile * 16 + (lane & 15);
        const int k = ktile * 32 + ((lane >> 4) << 3) + j;
        EtSw[x] = (_Float16)enc[(size_t)n * KK + k];
    }
    // SdSw: B-fragments for the decode GEMM. Per (nt,w): 16 ktiles x 64 lanes x 8.
    // k = local neuron = ktile*32 + (lane>>4)*8 + j ; col c = w*16 + (lane&15).
    _Float16* SdSw = (_Float16*)(ws + SDSW_OFF);
    for (size_t x = i; x < (size_t)NN * DS; x += stride) {
        const int j     = (int)(x & 7);
        const int lane  = (int)((x >> 3) & 63);
        const int ktile = (int)((x >> 9) & 15);
        const int w     = (int)((x >> 13) & 3);
        const int ntq   = (int)(x >> 15);
        const int n = ntq * 512 + ktile * 32 + ((lane >> 4) << 3) + j;
        const int c = w * 16 + (lane & 15);
        SdSw[x] = (_Float16)sd[(size_t)n * DS + c];
    }
    for (size_t x = i; x < (size_t)B_ * DOUT; x += stride) out[x] = 0.0f;
}

// R7 protocol (fence-free sc1 exchange, monotonic per-column counters,
// double-buffered fp32 ps, poll hidden mid-encode) + R11 MFMA encode.
// R12: decode also on MFMA — wave w computes state cols [16w,16w+16) over all
// 512 neurons (16 MFMA, no cross-wave reduce). Activations round-trip through
// LDS as f16 (Ash rows 4..15 uninitialized: they only feed discarded C rows).
__global__ __launch_bounds__(THREADS, 2) void persist_kernel(
    const float* __restrict__ seq,          // [B][T][DIN]
    const _Float16* __restrict__ EtSw,      // encoder B-fragments
    const _Float16* __restrict__ SdSw,      // state-decoder B-fragments
    const float* __restrict__ bias,
    const float* __restrict__ gain,
    const float* __restrict__ dec,   // [NN][DOUT]
    float* __restrict__ ps,          // [2][BTILES][NTILES][BT][DS]
    unsigned int* __restrict__ bar,  // cnt[BTILES * 32]
    float* __restrict__ out)
{
    __shared__ _Float16 xh[16][136];  // x_aug f16 (A-operand), rows 4..15 zero
    __shared__ _Float16 Ash[16][520]; // activations f16 (A-operand for decode)

    const int tid = threadIdx.x;
    const int nt = blockIdx.x & (NTILES - 1);
    const int bt = blockIdx.x >> 2;
    const int n0 = nt * NT;
    const int b0 = bt * BT;

    unsigned int* cnt = bar + (size_t)bt * 32;

    const int w = tid >> 6;            // wave 0..3
    const int l = tid & 63;            // lane
    const int rs = tid >> 6;           // s-exchange row 0..3
    const int cs = tid & 63;           // s-exchange col 0..63
    const int m16 = l & 15;            // fragment row/col index
    const int q8  = (l >> 4) << 3;     // fragment k sub-offset

    // per-wave swizzled-weight bases
    const _Float16* EtW = EtSw + ((size_t)(nt * 4 + w) << 14);
    const _Float16* SdW = SdSw + ((size_t)(nt * 4 + w) << 13);

    // loop-invariant epilogue params (lanes 0..15 use them)
    float gv[8], bv[8];
    #pragma unroll
    for (int n8 = 0; n8 < 8; ++n8) {
        gv[n8] = gain[n0 + w * 128 + n8 * 16 + m16];
        bv[n8] = bias[n0 + w * 128 + n8 * 16 + m16];
    }

    // zero xh once (rows 4..15 stay zero; rows 0..3 rewritten per step)
    {
        unsigned int* xz = (unsigned int*)&xh[0][0];
        for (int i2 = tid; i2 < 16 * 136 / 2; i2 += THREADS) xz[i2] = 0u;
    }
    __syncthreads();

    for (int t = 0; t < T_; ++t) {
        // ---- stage u_t into xh rows 0..3, k 0..63 ----
        if (tid < 64) {
            const int r = tid >> 4, c = (tid & 15) << 2;
            const float4 uv = *(const float4*)&seq[((size_t)(b0 + r) * T_ + t) * DIN + c];
            _Float16* p = &xh[r][c];
            p[0] = (_Float16)uv.x; p[1] = (_Float16)uv.y;
            p[2] = (_Float16)uv.z; p[3] = (_Float16)uv.w;
        }
        __syncthreads();

        // ---- encode phase A: k-tiles 0,1 (input half; hides the poll) ----
        f32x4 acc[8];
        #pragma unroll
        for (int n8 = 0; n8 < 8; ++n8) acc[n8] = (f32x4){0.f, 0.f, 0.f, 0.f};
        {
            const half8 af0 = *(const half8*)&xh[m16][q8];
            const half8 af1 = *(const half8*)&xh[m16][32 + q8];
            #pragma unroll
            for (int n8 = 0; n8 < 8; ++n8) {
                const half8 b0 = *(const half8*)&EtW[(n8 << 11) + (size_t)l * 8];
                const half8 b1 = *(const half8*)&EtW[(n8 << 11) + (1 << 9) + (size_t)l * 8];
                acc[n8] = __builtin_amdgcn_mfma_f32_16x16x32_f16(af0, b0, acc[n8], 0, 0, 0);
                acc[n8] = __builtin_amdgcn_mfma_f32_16x16x32_f16(af1, b1, acc[n8], 0, 0, 0);
            }
        }

        // ---- acquire state s(t-1): poll + coalesced sc1 fan-in (R7 verbatim) ----
        if (t > 0) {
            if (tid == 0) {
                while (__hip_atomic_load(cnt, __ATOMIC_RELAXED, __HIP_MEMORY_SCOPE_AGENT)
                       < 4u * (unsigned)t)
                    __builtin_amdgcn_s_sleep(1);
            }
            __syncthreads();
            const float* pb = ps + (size_t)((t - 1) & 1) * PS1;
            float ssum = 0.f;
            #pragma unroll
            for (int p = 0; p < NTILES; ++p)
                ssum += __hip_atomic_load(
                    pb + (((size_t)bt * NTILES + p) * BT + rs) * DS + cs,
                    __ATOMIC_RELAXED, __HIP_MEMORY_SCOPE_AGENT);
            xh[rs][DIN + cs] = (_Float16)ssum;
        } else {
            xh[rs][DIN + cs] = (_Float16)0.f;
        }
        __syncthreads();

        // ---- encode phase B: k-tiles 2,3 (state half) ----
        {
            const half8 af2 = *(const half8*)&xh[m16][64 + q8];
            const half8 af3 = *(const half8*)&xh[m16][96 + q8];
            #pragma unroll
            for (int n8 = 0; n8 < 8; ++n8) {
                const half8 b2 = *(const half8*)&EtW[(n8 << 11) + (2 << 9) + (size_t)l * 8];
                const half8 b3 = *(const half8*)&EtW[(n8 << 11) + (3 << 9) + (size_t)l * 8];
                acc[n8] = __builtin_amdgcn_mfma_f32_16x16x32_f16(af2, b2, acc[n8], 0, 0, 0);
                acc[n8] = __builtin_amdgcn_mfma_f32_16x16x32_f16(af3, b3, acc[n8], 0, 0, 0);
            }
        }

        // ---- epilogue: lanes 0..15 hold rows 0..3; write activations f16 ----
        if (l < 16) {
            #pragma unroll
            for (int n8 = 0; n8 < 8; ++n8) {
                const int n = w * 128 + n8 * 16 + m16;
                Ash[0][n] = (_Float16)fabsf(gv[n8] * acc[n8][0] + bv[n8]);
                Ash[1][n] = (_Float16)fabsf(gv[n8] * acc[n8][1] + bv[n8]);
                Ash[2][n] = (_Float16)fabsf(gv[n8] * acc[n8][2] + bv[n8]);
                Ash[3][n] = (_Float16)fabsf(gv[n8] * acc[n8][3] + bv[n8]);
            }
        }
        __syncthreads();

        if (t == T_ - 1) {
            // ---- final projection: out += A_tile @ dec_tile ----
            for (int idx = tid; idx < BT * DOUT; idx += THREADS) {
                const int r = idx / DOUT;
                const int d = idx % DOUT;
                float o = 0.f;
                #pragma unroll 8
                for (int n = 0; n < NT; ++n)
                    o += (float)Ash[r][n] * dec[(size_t)(n0 + n) * DOUT + d];
                atomicAdd(&out[(size_t)(b0 + r) * DOUT + d], o);
            }
            return;
        }

        // ---- decode on MFMA: wave w -> state cols [16w,16w+16), K=512 ----
        {
            f32x4 d0 = (f32x4){0.f, 0.f, 0.f, 0.f};
            f32x4 d1 = (f32x4){0.f, 0.f, 0.f, 0.f};
            #pragma unroll
            for (int kt = 0; kt < 16; kt += 2) {
                const half8 a0 = *(const half8*)&Ash[m16][kt * 32 + q8];
                const half8 bq0 = *(const half8*)&SdW[(kt << 9) + (size_t)l * 8];
                d0 = __builtin_amdgcn_mfma_f32_16x16x32_f16(a0, bq0, d0, 0, 0, 0);
                const half8 a1 = *(const half8*)&Ash[m16][(kt + 1) * 32 + q8];
                const half8 bq1 = *(const half8*)&SdW[((kt + 1) << 9) + (size_t)l * 8];
                d1 = __builtin_amdgcn_mfma_f32_16x16x32_f16(a1, bq1, d1, 0, 0, 0);
            }
            d0[0] += d1[0]; d0[1] += d1[1]; d0[2] += d1[2]; d0[3] += d1[3];
            // C/D: col=lane&15 -> state col 16w+m16; rows 0..3 in lanes 0..15
            if (l < 16) {
                float* pw = ps + (size_t)(t & 1) * PS1
                               + (((size_t)bt * NTILES + nt) * BT) * DS + 16 * w + m16;
                __hip_atomic_store(pw + 0*DS, d0[0], __ATOMIC_RELAXED, __HIP_MEMORY_SCOPE_AGENT);
                __hip_atomic_store(pw + 1*DS, d0[1], __ATOMIC_RELAXED, __HIP_MEMORY_SCOPE_AGENT);
                __hip_atomic_store(pw + 2*DS, d0[2], __ATOMIC_RELAXED, __HIP_MEMORY_SCOPE_AGENT);
                __hip_atomic_store(pw + 3*DS, d0[3], __ATOMIC_RELAXED, __HIP_MEMORY_SCOPE_AGENT);
            }
        }

        // ---- arrive: drain sc1 stores, bump generation (R7 verbatim) ----
        asm volatile("s_waitcnt vmcnt(0)" ::: "memory");
        __syncthreads();
        if (tid == 0)
            __hip_atomic_fetch_add(cnt, 1u, __ATOMIC_RELAXED, __HIP_MEMORY_SCOPE_AGENT);
    }
}

extern "C" void kernel_launch(void* const* d_in, const int* in_sizes, int n_in,
                              void* d_out, int out_size, void* d_ws, size_t ws_size,
                              hipStream_t stream) {
    const float* seq  = (const float*)d_in[0];
    const float* enc  = (const float*)d_in[1];
    const float* bias = (const float*)d_in[2];
    const float* gain = (const float*)d_in[3];
    const float* sd   = (const float*)d_in[4];
    const float* dec  = (const float*)d_in[5];
    float* out = (float*)d_out;
    float* ws  = (float*)d_ws;   // ps[2] | EtSw | SdSw | counters  (~1.8 MB)

    pre_kernel<<<dim3(1024), dim3(256), 0, stream>>>(enc, sd, ws, out);

    float* ps = ws;
    const _Float16* EtSw = (const _Float16*)(ws + ETSW_OFF);
    const _Float16* SdSw = (const _Float16*)(ws + SDSW_OFF);
    unsigned int* bar = (unsigned int*)(ws + BAR_OFF);

    persist_kernel<<<dim3(NWG), dim3(THREADS), 0, stream>>>(
        seq, EtSw, SdSw, bias, gain, dec, ps, bar, out);
}

// Round 13
// 765.142 us; speedup vs baseline: 26.8338x; 1.6204x over previous
//
#include <hip/hip_runtime.h>
#include <math.h>

// Problem constants
#define B_    512
#define T_    256
#define DIN   64
#define DS    64
#define KK    128   // DIN + DS
#define NN    2048
#define DOUT  10

// Tiling: 256 WGs = NTILES(4) x BTILES(64), 512 thr (8 waves), 1 WG/CU.
// BT=8 halves per-CU weight streaming vs R12's BT=4 (the binding term).
#define NT      512
#define BT      8
#define NTILES  (NN / NT)      // 4
#define BTILES  (B_ / BT)      // 64
#define THREADS 512
#define NWG     (NTILES * BTILES)   // 256

// Workspace (float offsets): ps[2] | EtSw (f16 B-frags) | SdSw (f16 B-frags) | counters
#define PS1        ((size_t)BTILES * NTILES * BT * DS)   // 131072 floats (512 KB)
#define PS_TOT     (2 * PS1)
#define ETSW_OFF   PS_TOT
#define ETSW_F16   ((size_t)KK * NN)                     // 262144 f16 = 512 KB
#define SDSW_OFF   (ETSW_OFF + ETSW_F16 / 2)
#define SDSW_F16   ((size_t)NN * DS)                     // 131072 f16 = 256 KB
#define BAR_OFF    (SDSW_OFF + SDSW_F16 / 2)
#define BAR_UINTS  4096

typedef _Float16 half8 __attribute__((ext_vector_type(8)));
typedef float    f32x4 __attribute__((ext_vector_type(4)));

__global__ __launch_bounds__(256) void pre_kernel(const float* __restrict__ enc,
                                                  const float* __restrict__ sd,
                                                  float* __restrict__ ws,
                                                  float* __restrict__ out) {
    size_t i = (size_t)blockIdx.x * blockDim.x + threadIdx.x;
    size_t stride = (size_t)gridDim.x * blockDim.x;
    unsigned int* bar = (unsigned int*)(ws + BAR_OFF);
    for (size_t x = i; x < BAR_UINTS; x += stride) bar[x] = 0u;
    // EtSw: B-fragments, 8-wave ownership.
    // x = ((((nt*8 + w)*4 + ntile)*4 + ktile)*64 + lane)*8 + j
    // n = nt*512 + w*64 + ntile*16 + (lane&15); k = ktile*32 + (lane>>4)*8 + j
    _Float16* EtSw = (_Float16*)(ws + ETSW_OFF);
    for (size_t x = i; x < (size_t)KK * NN; x += stride) {
        const int j     = (int)(x & 7);
        const int lane  = (int)((x >> 3) & 63);
        const int ktile = (int)((x >> 9) & 3);
        const int ntile = (int)((x >> 11) & 3);
        const int w     = (int)((x >> 13) & 7);
        const int nt    = (int)(x >> 16);
        const int n = nt * 512 + w * 64 + ntile * 16 + (lane & 15);
        const int k = ktile * 32 + ((lane >> 4) << 3) + j;
        EtSw[x] = (_Float16)enc[(size_t)n * KK + k];
    }
    // SdSw: decode B-fragments. Wave (cg,kh): cols cg*16+(lane&15), neuron half kh.
    // x = ((((nt*4 + cg)*2 + kh)*8 + ktile)*64 + lane)*8 + j
    // n = nt*512 + kh*256 + ktile*32 + (lane>>4)*8 + j ; c = cg*16 + (lane&15)
    _Float16* SdSw = (_Float16*)(ws + SDSW_OFF);
    for (size_t x = i; x < (size_t)NN * DS; x += stride) {
        const int j     = (int)(x & 7);
        const int lane  = (int)((x >> 3) & 63);
        const int ktile = (int)((x >> 9) & 7);
        const int kh    = (int)((x >> 12) & 1);
        const int cg    = (int)((x >> 13) & 3);
        const int nt    = (int)(x >> 15);
        const int n = nt * 512 + kh * 256 + ktile * 32 + ((lane >> 4) << 3) + j;
        const int c = cg * 16 + (lane & 15);
        SdSw[x] = (_Float16)sd[(size_t)n * DS + c];
    }
    for (size_t x = i; x < (size_t)B_ * DOUT; x += stride) out[x] = 0.0f;
}

// R7 protocol + R11/R12 MFMA compute. R13: BT=8 / 512-thread WGs / 1 WG/CU —
// same 8 waves/CU, half the per-CU weight bytes. Encode wave w: 64 neurons,
// 16 MFMA (rows 0-7 real, lanes 0-31). Decode wave (cg,kh): 16 cols x 256
// neurons, 8 MFMA, 2-way LDS reduce across kh.
__global__ __launch_bounds__(THREADS, 2) void persist_kernel(
    const float* __restrict__ seq,          // [B][T][DIN]
    const _Float16* __restrict__ EtSw,      // encoder B-fragments
    const _Float16* __restrict__ SdSw,      // state-decoder B-fragments
    const float* __restrict__ bias,
    const float* __restrict__ gain,
    const float* __restrict__ dec,   // [NN][DOUT]
    float* __restrict__ ps,          // [2][BTILES][NTILES][BT][DS]
    unsigned int* __restrict__ bar,  // cnt[BTILES * 32]
    float* __restrict__ out)
{
    __shared__ _Float16 xh[16][136];  // x_aug f16 (A-operand), rows 8..15 zero
    __shared__ _Float16 Ash[16][520]; // activations f16 (A-operand for decode)
    __shared__ float Dp[4][8][17];    // decode kh-pair partials

    const int tid = threadIdx.x;
    const int nt = blockIdx.x & (NTILES - 1);
    const int bt = blockIdx.x >> 2;
    const int n0 = nt * NT;
    const int b0 = bt * BT;

    unsigned int* cnt = bar + (size_t)bt * 32;

    const int w = tid >> 6;            // wave 0..7
    const int l = tid & 63;
    const int rs = tid >> 6;           // fan-in row 0..7
    const int cs = tid & 63;           // fan-in col
    const int m16 = l & 15;            // fragment row/col index
    const int q8  = (l >> 4) << 3;     // fragment k sub-offset
    const int cg  = w & 3;             // decode col group
    const int kh  = w >> 2;            // decode neuron half

    const _Float16* EtW = EtSw + ((size_t)(nt * 8 + w) << 13);
    const _Float16* SdW = SdSw + ((size_t)((nt * 4 + cg) * 2 + kh) << 12);

    // epilogue params: 4 n-tiles of 16 per wave
    float gv[4], bv[4];
    #pragma unroll
    for (int n4 = 0; n4 < 4; ++n4) {
        gv[n4] = gain[n0 + w * 64 + n4 * 16 + m16];
        bv[n4] = bias[n0 + w * 64 + n4 * 16 + m16];
    }

    // zero xh once (rows 8..15 stay zero; rows 0..7 rewritten per step)
    {
        unsigned int* xz = (unsigned int*)&xh[0][0];
        for (int i2 = tid; i2 < 16 * 136 / 2; i2 += THREADS) xz[i2] = 0u;
    }
    __syncthreads();

    for (int t = 0; t < T_; ++t) {
        // ---- stage u_t into xh rows 0..7, k 0..63 ----
        if (tid < 128) {
            const int r = tid >> 4, c = (tid & 15) << 2;
            const float4 uv = *(const float4*)&seq[((size_t)(b0 + r) * T_ + t) * DIN + c];
            _Float16* p = &xh[r][c];
            p[0] = (_Float16)uv.x; p[1] = (_Float16)uv.y;
            p[2] = (_Float16)uv.z; p[3] = (_Float16)uv.w;
        }
        __syncthreads();

        // ---- encode phase A: k-tiles 0,1 (input half; hides the poll) ----
        f32x4 acc[4];
        #pragma unroll
        for (int n4 = 0; n4 < 4; ++n4) acc[n4] = (f32x4){0.f, 0.f, 0.f, 0.f};
        {
            const half8 af0 = *(const half8*)&xh[m16][q8];
            const half8 af1 = *(const half8*)&xh[m16][32 + q8];
            #pragma unroll
            for (int n4 = 0; n4 < 4; ++n4) {
                const half8 bq0 = *(const half8*)&EtW[(n4 << 11) + (size_t)l * 8];
                const half8 bq1 = *(const half8*)&EtW[(n4 << 11) + (1 << 9) + (size_t)l * 8];
                acc[n4] = __builtin_amdgcn_mfma_f32_16x16x32_f16(af0, bq0, acc[n4], 0, 0, 0);
                acc[n4] = __builtin_amdgcn_mfma_f32_16x16x32_f16(af1, bq1, acc[n4], 0, 0, 0);
            }
        }

        // ---- acquire state s(t-1): poll + coalesced sc1 fan-in ----
        if (t > 0) {
            if (tid == 0) {
                while (__hip_atomic_load(cnt, __ATOMIC_RELAXED, __HIP_MEMORY_SCOPE_AGENT)
                       < 4u * (unsigned)t)
                    __builtin_amdgcn_s_sleep(1);
            }
            __syncthreads();
            const float* pb = ps + (size_t)((t - 1) & 1) * PS1;
            float ssum = 0.f;
            #pragma unroll
            for (int p = 0; p < NTILES; ++p)
                ssum += __hip_atomic_load(
                    pb + (((size_t)bt * NTILES + p) * BT + rs) * DS + cs,
                    __ATOMIC_RELAXED, __HIP_MEMORY_SCOPE_AGENT);
            xh[rs][DIN + cs] = (_Float16)ssum;
        } else {
            xh[rs][DIN + cs] = (_Float16)0.f;
        }
        __syncthreads();

        // ---- encode phase B: k-tiles 2,3 (state half) ----
        {
            const half8 af2 = *(const half8*)&xh[m16][64 + q8];
            const half8 af3 = *(const half8*)&xh[m16][96 + q8];
            #pragma unroll
            for (int n4 = 0; n4 < 4; ++n4) {
                const half8 bq2 = *(const half8*)&EtW[(n4 << 11) + (2 << 9) + (size_t)l * 8];
                const half8 bq3 = *(const half8*)&EtW[(n4 << 11) + (3 << 9) + (size_t)l * 8];
                acc[n4] = __builtin_amdgcn_mfma_f32_16x16x32_f16(af2, bq2, acc[n4], 0, 0, 0);
                acc[n4] = __builtin_amdgcn_mfma_f32_16x16x32_f16(af3, bq3, acc[n4], 0, 0, 0);
            }
        }

        // ---- epilogue: rows 0..7 live in lanes 0..31 (row=(l>>4)*4+reg) ----
        if (l < 32) {
            const int rq = (l >> 4) << 2;
            #pragma unroll
            for (int n4 = 0; n4 < 4; ++n4) {
                const int n = w * 64 + n4 * 16 + m16;
                Ash[rq + 0][n] = (_Float16)fabsf(gv[n4] * acc[n4][0] + bv[n4]);
                Ash[rq + 1][n] = (_Float16)fabsf(gv[n4] * acc[n4][1] + bv[n4]);
                Ash[rq + 2][n] = (_Float16)fabsf(gv[n4] * acc[n4][2] + bv[n4]);
                Ash[rq + 3][n] = (_Float16)fabsf(gv[n4] * acc[n4][3] + bv[n4]);
            }
        }
        __syncthreads();

        if (t == T_ - 1) {
            // ---- final projection: out += A_tile @ dec_tile ----
            for (int idx = tid; idx < BT * DOUT; idx += THREADS) {
                const int r = idx / DOUT;
                const int d = idx % DOUT;
                float o = 0.f;
                #pragma unroll 8
                for (int n = 0; n < NT; ++n)
                    o += (float)Ash[r][n] * dec[(size_t)(n0 + n) * DOUT + d];
                atomicAdd(&out[(size_t)(b0 + r) * DOUT + d], o);
            }
            return;
        }

        // ---- decode on MFMA: wave (cg,kh) -> cols [16cg,+16), neurons [256kh,+256) ----
        {
            f32x4 d0 = (f32x4){0.f, 0.f, 0.f, 0.f};
            f32x4 d1 = (f32x4){0.f, 0.f, 0.f, 0.f};
            #pragma unroll
            for (int kt = 0; kt < 8; kt += 2) {
                const half8 a0 = *(const half8*)&Ash[m16][kh * 256 + kt * 32 + q8];
                const half8 bq0 = *(const half8*)&SdW[(kt << 9) + (size_t)l * 8];
                d0 = __builtin_amdgcn_mfma_f32_16x16x32_f16(a0, bq0, d0, 0, 0, 0);
                const half8 a1 = *(const half8*)&Ash[m16][kh * 256 + (kt + 1) * 32 + q8];
                const half8 bq1 = *(const half8*)&SdW[((kt + 1) << 9) + (size_t)l * 8];
                d1 = __builtin_amdgcn_mfma_f32_16x16x32_f16(a1, bq1, d1, 0, 0, 0);
            }
            d0[0] += d1[0]; d0[1] += d1[1]; d0[2] += d1[2]; d0[3] += d1[3];
            // kh=1 publishes; kh=0 adds and stores (rows 0..7 in lanes 0..31)
            if (kh == 1 && l < 32) {
                const int rq = (l >> 4) << 2;
                Dp[cg][rq + 0][m16] = d0[0];
                Dp[cg][rq + 1][m16] = d0[1];
                Dp[cg][rq + 2][m16] = d0[2];
                Dp[cg][rq + 3][m16] = d0[3];
            }
            __syncthreads();
            if (kh == 0 && l < 32) {
                const int rq = (l >> 4) << 2;
                float* pw = ps + (size_t)(t & 1) * PS1
                               + (((size_t)bt * NTILES + nt) * BT) * DS + 16 * cg + m16;
                #pragma unroll
                for (int r = 0; r < 4; ++r) {
                    const float v = d0[r] + Dp[cg][rq + r][m16];
                    __hip_atomic_store(pw + (size_t)(rq + r) * DS, v,
                                       __ATOMIC_RELAXED, __HIP_MEMORY_SCOPE_AGENT);
                }
            }
        }

        // ---- arrive: drain sc1 stores, bump generation ----
        asm volatile("s_waitcnt vmcnt(0)" ::: "memory");
        __syncthreads();
        if (tid == 0)
            __hip_atomic_fetch_add(cnt, 1u, __ATOMIC_RELAXED, __HIP_MEMORY_SCOPE_AGENT);
    }
}

extern "C" void kernel_launch(void* const* d_in, const int* in_sizes, int n_in,
                              void* d_out, int out_size, void* d_ws, size_t ws_size,
                              hipStream_t stream) {
    const float* seq  = (const float*)d_in[0];
    const float* enc  = (const float*)d_in[1];
    const float* bias = (const float*)d_in[2];
    const float* gain = (const float*)d_in[3];
    const float* sd   = (const float*)d_in[4];
    const float* dec  = (const float*)d_in[5];
    float* out = (float*)d_out;
    float* ws  = (float*)d_ws;   // ps[2] | EtSw | SdSw | counters  (~1.8 MB)

    pre_kernel<<<dim3(1024), dim3(256), 0, stream>>>(enc, sd, ws, out);

    float* ps = ws;
    const _Float16* EtSw = (const _Float16*)(ws + ETSW_OFF);
    const _Float16* SdSw = (const _Float16*)(ws + SDSW_OFF);
    unsigned int* bar = (unsigned int*)(ws + BAR_OFF);

    persist_kernel<<<dim3(NWG), dim3(THREADS), 0, stream>>>(
        seq, EtSw, SdSw, bias, gain, dec, ps, bar, out);
}

// Round 14
// 660.557 us; speedup vs baseline: 31.0823x; 1.1583x over previous
//
#include <hip/hip_runtime.h>
#include <math.h>

// Problem constants
#define B_    512
#define T_    256
#define DIN   64
#define DS    64
#define KK    128   // DIN + DS
#define NN    2048
#define DOUT  10

// Tiling: 256 WGs = NTILES(4) x BTILES(64), 512 thr (8 waves), 1 WG/CU.
#define NT      512
#define BT      8
#define NTILES  (NN / NT)      // 4
#define BTILES  (B_ / BT)      // 64
#define THREADS 512
#define NWG     (NTILES * BTILES)   // 256

// Workspace (float offsets): ps[2] | EtSw (f16 B-frags) | SdSw (f16 B-frags) | counters
#define PS1        ((size_t)BTILES * NTILES * BT * DS)   // 131072 floats (512 KB)
#define PS_TOT     (2 * PS1)
#define ETSW_OFF   PS_TOT
#define ETSW_F16   ((size_t)KK * NN)                     // 262144 f16 = 512 KB
#define SDSW_OFF   (ETSW_OFF + ETSW_F16 / 2)
#define SDSW_F16   ((size_t)NN * DS)                     // 131072 f16 = 256 KB
#define BAR_OFF    (SDSW_OFF + SDSW_F16 / 2)
#define BAR_UINTS  4096

typedef _Float16 half8 __attribute__((ext_vector_type(8)));
typedef float    f32x4 __attribute__((ext_vector_type(4)));

__global__ __launch_bounds__(256) void pre_kernel(const float* __restrict__ enc,
                                                  const float* __restrict__ sd,
                                                  float* __restrict__ ws,
                                                  float* __restrict__ out) {
    size_t i = (size_t)blockIdx.x * blockDim.x + threadIdx.x;
    size_t stride = (size_t)gridDim.x * blockDim.x;
    unsigned int* bar = (unsigned int*)(ws + BAR_OFF);
    for (size_t x = i; x < BAR_UINTS; x += stride) bar[x] = 0u;
    // EtSw: B-fragments, 8-wave ownership (R13-verified).
    _Float16* EtSw = (_Float16*)(ws + ETSW_OFF);
    for (size_t x = i; x < (size_t)KK * NN; x += stride) {
        const int j     = (int)(x & 7);
        const int lane  = (int)((x >> 3) & 63);
        const int ktile = (int)((x >> 9) & 3);
        const int ntile = (int)((x >> 11) & 3);
        const int w     = (int)((x >> 13) & 7);
        const int nt    = (int)(x >> 16);
        const int n = nt * 512 + w * 64 + ntile * 16 + (lane & 15);
        const int k = ktile * 32 + ((lane >> 4) << 3) + j;
        EtSw[x] = (_Float16)enc[(size_t)n * KK + k];
    }
    // SdSw: decode B-fragments (R13-verified).
    _Float16* SdSw = (_Float16*)(ws + SDSW_OFF);
    for (size_t x = i; x < (size_t)NN * DS; x += stride) {
        const int j     = (int)(x & 7);
        const int lane  = (int)((x >> 3) & 63);
        const int ktile = (int)((x >> 9) & 7);
        const int kh    = (int)((x >> 12) & 1);
        const int cg    = (int)((x >> 13) & 3);
        const int nt    = (int)(x >> 15);
        const int n = nt * 512 + kh * 256 + ktile * 32 + ((lane >> 4) << 3) + j;
        const int c = cg * 16 + (lane & 15);
        SdSw[x] = (_Float16)sd[(size_t)n * DS + c];
    }
    for (size_t x = i; x < (size_t)B_ * DOUT; x += stride) out[x] = 0.0f;
}

// R13 structure (proven 765 us) with ONE change: all MFMA weight fragments
// (16 encode half8 + 8 decode half8 per wave = 96 VGPRs) are loaded ONCE
// before the t-loop and stay register-resident — per-step L2 weight
// streaming (192 KB/CU, the ~1.3 us binding term) drops to zero, and the
// post-poll critical path has no memory dependency beyond the sc1 fan-in.
// VGPR budget: 8 waves/CU = 2 waves/SIMD -> 256 VGPR cap; est ~170 used.
__global__ __launch_bounds__(THREADS, 2) void persist_kernel(
    const float* __restrict__ seq,          // [B][T][DIN]
    const _Float16* __restrict__ EtSw,      // encoder B-fragments
    const _Float16* __restrict__ SdSw,      // state-decoder B-fragments
    const float* __restrict__ bias,
    const float* __restrict__ gain,
    const float* __restrict__ dec,   // [NN][DOUT]
    float* __restrict__ ps,          // [2][BTILES][NTILES][BT][DS]
    unsigned int* __restrict__ bar,  // cnt[BTILES * 32]
    float* __restrict__ out)
{
    __shared__ _Float16 xh[16][136];  // x_aug f16 (A-operand), rows 8..15 zero
    __shared__ _Float16 Ash[16][520]; // activations f16 (A-operand for decode)
    __shared__ float Dp[4][8][17];    // decode kh-pair partials

    const int tid = threadIdx.x;
    const int nt = blockIdx.x & (NTILES - 1);
    const int bt = blockIdx.x >> 2;
    const int n0 = nt * NT;
    const int b0 = bt * BT;

    unsigned int* cnt = bar + (size_t)bt * 32;

    const int w = tid >> 6;            // wave 0..7
    const int l = tid & 63;
    const int rs = tid >> 6;           // fan-in row 0..7
    const int cs = tid & 63;           // fan-in col
    const int m16 = l & 15;            // fragment row/col index
    const int q8  = (l >> 4) << 3;     // fragment k sub-offset
    const int cg  = w & 3;             // decode col group
    const int kh  = w >> 2;            // decode neuron half

    const _Float16* EtW = EtSw + ((size_t)(nt * 8 + w) << 13);
    const _Float16* SdW = SdSw + ((size_t)((nt * 4 + cg) * 2 + kh) << 12);

    // ---- register-resident weight fragments (loaded once) ----
    half8 etf[4][4];   // [ntile][ktile]
    #pragma unroll
    for (int n4 = 0; n4 < 4; ++n4)
        #pragma unroll
        for (int kt = 0; kt < 4; ++kt)
            etf[n4][kt] = *(const half8*)&EtW[(n4 << 11) + (kt << 9) + (size_t)l * 8];
    half8 sdf[8];
    #pragma unroll
    for (int kt = 0; kt < 8; ++kt)
        sdf[kt] = *(const half8*)&SdW[(kt << 9) + (size_t)l * 8];

    // epilogue params: 4 n-tiles of 16 per wave
    float gv[4], bv[4];
    #pragma unroll
    for (int n4 = 0; n4 < 4; ++n4) {
        gv[n4] = gain[n0 + w * 64 + n4 * 16 + m16];
        bv[n4] = bias[n0 + w * 64 + n4 * 16 + m16];
    }

    // zero xh once (rows 8..15 stay zero; rows 0..7 rewritten per step)
    {
        unsigned int* xz = (unsigned int*)&xh[0][0];
        for (int i2 = tid; i2 < 16 * 136 / 2; i2 += THREADS) xz[i2] = 0u;
    }
    __syncthreads();

    for (int t = 0; t < T_; ++t) {
        // ---- stage u_t into xh rows 0..7, k 0..63 ----
        if (tid < 128) {
            const int r = tid >> 4, c = (tid & 15) << 2;
            const float4 uv = *(const float4*)&seq[((size_t)(b0 + r) * T_ + t) * DIN + c];
            _Float16* p = &xh[r][c];
            p[0] = (_Float16)uv.x; p[1] = (_Float16)uv.y;
            p[2] = (_Float16)uv.z; p[3] = (_Float16)uv.w;
        }
        __syncthreads();

        // ---- encode phase A: k-tiles 0,1 (input half; hides the poll) ----
        f32x4 acc[4];
        #pragma unroll
        for (int n4 = 0; n4 < 4; ++n4) acc[n4] = (f32x4){0.f, 0.f, 0.f, 0.f};
        {
            const half8 af0 = *(const half8*)&xh[m16][q8];
            const half8 af1 = *(const half8*)&xh[m16][32 + q8];
            #pragma unroll
            for (int n4 = 0; n4 < 4; ++n4) {
                acc[n4] = __builtin_amdgcn_mfma_f32_16x16x32_f16(af0, etf[n4][0], acc[n4], 0, 0, 0);
                acc[n4] = __builtin_amdgcn_mfma_f32_16x16x32_f16(af1, etf[n4][1], acc[n4], 0, 0, 0);
            }
        }

        // ---- acquire state s(t-1): poll + coalesced sc1 fan-in ----
        if (t > 0) {
            if (tid == 0) {
                while (__hip_atomic_load(cnt, __ATOMIC_RELAXED, __HIP_MEMORY_SCOPE_AGENT)
                       < 4u * (unsigned)t)
                    __builtin_amdgcn_s_sleep(1);
            }
            __syncthreads();
            const float* pb = ps + (size_t)((t - 1) & 1) * PS1;
            float ssum = 0.f;
            #pragma unroll
            for (int p = 0; p < NTILES; ++p)
                ssum += __hip_atomic_load(
                    pb + (((size_t)bt * NTILES + p) * BT + rs) * DS + cs,
                    __ATOMIC_RELAXED, __HIP_MEMORY_SCOPE_AGENT);
            xh[rs][DIN + cs] = (_Float16)ssum;
        } else {
            xh[rs][DIN + cs] = (_Float16)0.f;
        }
        __syncthreads();

        // ---- encode phase B: k-tiles 2,3 (state half) ----
        {
            const half8 af2 = *(const half8*)&xh[m16][64 + q8];
            const half8 af3 = *(const half8*)&xh[m16][96 + q8];
            #pragma unroll
            for (int n4 = 0; n4 < 4; ++n4) {
                acc[n4] = __builtin_amdgcn_mfma_f32_16x16x32_f16(af2, etf[n4][2], acc[n4], 0, 0, 0);
                acc[n4] = __builtin_amdgcn_mfma_f32_16x16x32_f16(af3, etf[n4][3], acc[n4], 0, 0, 0);
            }
        }

        // ---- epilogue: rows 0..7 live in lanes 0..31 (row=(l>>4)*4+reg) ----
        if (l < 32) {
            const int rq = (l >> 4) << 2;
            #pragma unroll
            for (int n4 = 0; n4 < 4; ++n4) {
                const int n = w * 64 + n4 * 16 + m16;
                Ash[rq + 0][n] = (_Float16)fabsf(gv[n4] * acc[n4][0] + bv[n4]);
                Ash[rq + 1][n] = (_Float16)fabsf(gv[n4] * acc[n4][1] + bv[n4]);
                Ash[rq + 2][n] = (_Float16)fabsf(gv[n4] * acc[n4][2] + bv[n4]);
                Ash[rq + 3][n] = (_Float16)fabsf(gv[n4] * acc[n4][3] + bv[n4]);
            }
        }
        __syncthreads();

        if (t == T_ - 1) {
            // ---- final projection: out += A_tile @ dec_tile ----
            for (int idx = tid; idx < BT * DOUT; idx += THREADS) {
                const int r = idx / DOUT;
                const int d = idx % DOUT;
                float o = 0.f;
                #pragma unroll 8
                for (int n = 0; n < NT; ++n)
                    o += (float)Ash[r][n] * dec[(size_t)(n0 + n) * DOUT + d];
                atomicAdd(&out[(size_t)(b0 + r) * DOUT + d], o);
            }
            return;
        }

        // ---- decode on MFMA: wave (cg,kh) -> cols [16cg,+16), neurons [256kh,+256) ----
        {
            f32x4 d0 = (f32x4){0.f, 0.f, 0.f, 0.f};
            f32x4 d1 = (f32x4){0.f, 0.f, 0.f, 0.f};
            #pragma unroll
            for (int kt = 0; kt < 8; kt += 2) {
                const half8 a0 = *(const half8*)&Ash[m16][kh * 256 + kt * 32 + q8];
                d0 = __builtin_amdgcn_mfma_f32_16x16x32_f16(a0, sdf[kt], d0, 0, 0, 0);
                const half8 a1 = *(const half8*)&Ash[m16][kh * 256 + (kt + 1) * 32 + q8];
                d1 = __builtin_amdgcn_mfma_f32_16x16x32_f16(a1, sdf[kt + 1], d1, 0, 0, 0);
            }
            d0[0] += d1[0]; d0[1] += d1[1]; d0[2] += d1[2]; d0[3] += d1[3];
            // kh=1 publishes; kh=0 adds and stores (rows 0..7 in lanes 0..31)
            if (kh == 1 && l < 32) {
                const int rq = (l >> 4) << 2;
                Dp[cg][rq + 0][m16] = d0[0];
                Dp[cg][rq + 1][m16] = d0[1];
                Dp[cg][rq + 2][m16] = d0[2];
                Dp[cg][rq + 3][m16] = d0[3];
            }
            __syncthreads();
            if (kh == 0 && l < 32) {
                const int rq = (l >> 4) << 2;
                float* pw = ps + (size_t)(t & 1) * PS1
                               + (((size_t)bt * NTILES + nt) * BT) * DS + 16 * cg + m16;
                #pragma unroll
                for (int r = 0; r < 4; ++r) {
                    const float v = d0[r] + Dp[cg][rq + r][m16];
                    __hip_atomic_store(pw + (size_t)(rq + r) * DS, v,
                                       __ATOMIC_RELAXED, __HIP_MEMORY_SCOPE_AGENT);
                }
            }
        }

        // ---- arrive: drain sc1 stores, bump generation ----
        asm volatile("s_waitcnt vmcnt(0)" ::: "memory");
        __syncthreads();
        if (tid == 0)
            __hip_atomic_fetch_add(cnt, 1u, __ATOMIC_RELAXED, __HIP_MEMORY_SCOPE_AGENT);
    }
}

extern "C" void kernel_launch(void* const* d_in, const int* in_sizes, int n_in,
                              void* d_out, int out_size, void* d_ws, size_t ws_size,
                              hipStream_t stream) {
    const float* seq  = (const float*)d_in[0];
    const float* enc  = (const float*)d_in[1];
    const float* bias = (const float*)d_in[2];
    const float* gain = (const float*)d_in[3];
    const float* sd   = (const float*)d_in[4];
    const float* dec  = (const float*)d_in[5];
    float* out = (float*)d_out;
    float* ws  = (float*)d_ws;   // ps[2] | EtSw | SdSw | counters  (~1.8 MB)

    pre_kernel<<<dim3(1024), dim3(256), 0, stream>>>(enc, sd, ws, out);

    float* ps = ws;
    const _Float16* EtSw = (const _Float16*)(ws + ETSW_OFF);
    const _Float16* SdSw = (const _Float16*)(ws + SDSW_OFF);
    unsigned int* bar = (unsigned int*)(ws + BAR_OFF);

    persist_kernel<<<dim3(NWG), dim3(THREADS), 0, stream>>>(
        seq, EtSw, SdSw, bias, gain, dec, ps, bar, out);
}